// Round 3
// baseline (719.916 us; speedup 1.0000x reference)
//
#include <hip/hip_runtime.h>
#include <hip/hip_bf16.h>
#include <math.h>

#define BB 8
#define SS 2048
#define HH 8
#define DKK 64
#define DM 512

typedef short bf16x8 __attribute__((ext_vector_type(8)));
typedef short bf16x4 __attribute__((ext_vector_type(4)));
typedef float f32x4 __attribute__((ext_vector_type(4)));
#define MFMA16(a, b, c) __builtin_amdgcn_mfma_f32_16x16x32_bf16(a, b, c, 0, 0, 0)

#if __has_builtin(__builtin_amdgcn_exp2f)
#define EXP2(x) __builtin_amdgcn_exp2f(x)
#else
#define EXP2(x) exp2f(x)
#endif

__device__ __forceinline__ unsigned short f2bf(float f) {
    __hip_bfloat16 h = __float2bfloat16(f);
    return *reinterpret_cast<unsigned short*>(&h);
}

// Convert 8 consecutive fp32 -> 8 bf16, return as uint4 for a 16B LDS store.
__device__ __forceinline__ uint4 cvt8(const float* __restrict__ src) {
    float4 a = *(const float4*)src;
    float4 b = *(const float4*)(src + 4);
    unsigned short tmp[8];
    tmp[0] = f2bf(a.x); tmp[1] = f2bf(a.y); tmp[2] = f2bf(a.z); tmp[3] = f2bf(a.w);
    tmp[4] = f2bf(b.x); tmp[5] = f2bf(b.y); tmp[6] = f2bf(b.z); tmp[7] = f2bf(b.w);
    return *(uint4*)tmp;
}

// ---------------------------------------------------------------------------
// Mask bit-pack: mask int32 [S][S] -> mb uint64 [S][S/64], bit i of word
// (q, c) = (mask[q][c*64+i] != 0). One wave per output word via __ballot.
// ---------------------------------------------------------------------------
__global__ __launch_bounds__(256) void mask_pack(
    const int* __restrict__ mask, unsigned long long* __restrict__ mb)
{
    const int t = threadIdx.x;
    const int wid = (blockIdx.x << 2) | (t >> 6);   // global wave id == word idx
    const int lane = t & 63;
    const int q = wid >> 5;          // / (SS/64)
    const int c = wid & 31;
    int e = mask[(size_t)q * SS + (c << 6) + lane];
    unsigned long long bal = __ballot(e != 0);
    if (lane == 0) mb[wid] = bal;
}

// ---------------------------------------------------------------------------
// Fused QKV projection (gridDim.z selects Q/K/V): out[m][n] =
// (sum_k X[m][k]*W[n][k] + bias[n]) * scale. Internals identical to the
// proven proj_qkv_mfma for the K-loop.
// z=0 (Q), z=1 (K): out bf16 scattered to [B*H][S][64] (n = h*64+d).
// z=2 (V): out written TRANSPOSED to [B*H][64][S] (so attn can stage the
//          V tile with clean uint4 copies; no separate transpose kernel,
//          no scratch outside the proven 64 MB ws). acc[mt][nt][r] over r
//          is 4 consecutive s -> one bf16x4 store per (mt,nt): 16x8B
//          stores/thread vs 64x2B of the scatter path, same coalescing.
// ---------------------------------------------------------------------------
__global__ __launch_bounds__(256, 2) void proj_qkv_fused(
    const float* __restrict__ Xq, const float* __restrict__ Xk, const float* __restrict__ Xv,
    const float* __restrict__ Wq, const float* __restrict__ Wk, const float* __restrict__ Wv,
    const float* __restrict__ bq, const float* __restrict__ bk, const float* __restrict__ bv,
    unsigned short* __restrict__ outbase, float qscale)
{
    const int z = blockIdx.z;
    const float* X = (z == 0) ? Xq : (z == 1) ? Xk : Xv;
    const float* W = (z == 0) ? Wq : (z == 1) ? Wk : Wv;
    const float* bias = (z == 0) ? bq : (z == 1) ? bk : bv;
    unsigned short* out = outbase + (size_t)z * ((size_t)BB * HH * SS * DKK);
    const float scale = (z == 0) ? qscale : 1.0f;

    __shared__ __align__(16) unsigned short Xs[128][72];
    __shared__ __align__(16) unsigned short Ws[128][72];
    const int t = threadIdx.x;
    const int w = t >> 6, l = t & 63;
    const int l15 = l & 15, lg = l >> 4;
    const int n0 = blockIdx.x * 128, m0 = blockIdx.y * 128;
    const int mo = (w & 1) * 64, no = (w >> 1) * 64;

    f32x4 acc[4][4];
#pragma unroll
    for (int i = 0; i < 4; i++)
#pragma unroll
        for (int j = 0; j < 4; j++) acc[i][j] = (f32x4){0.f, 0.f, 0.f, 0.f};

    for (int k0 = 0; k0 < DM; k0 += 64) {
        __syncthreads();
#pragma unroll
        for (int rr = 0; rr < 4; rr++) {
            int idx = rr * 2048 + t * 8;
            int row = idx >> 6, col = idx & 63;
            *(uint4*)&Xs[row][col] = cvt8(X + (size_t)(m0 + row) * DM + k0 + col);
            *(uint4*)&Ws[row][col] = cvt8(W + (size_t)(n0 + row) * DM + k0 + col);
        }
        __syncthreads();

        bf16x8 af[4][2], bfr[4][2];
#pragma unroll
        for (int mt = 0; mt < 4; mt++) {
            af[mt][0] = *(const bf16x8*)&Xs[mo + mt * 16 + l15][lg * 8];
            af[mt][1] = *(const bf16x8*)&Xs[mo + mt * 16 + l15][32 + lg * 8];
        }
#pragma unroll
        for (int nt = 0; nt < 4; nt++) {
            bfr[nt][0] = *(const bf16x8*)&Ws[no + nt * 16 + l15][lg * 8];
            bfr[nt][1] = *(const bf16x8*)&Ws[no + nt * 16 + l15][32 + lg * 8];
        }
#pragma unroll
        for (int mt = 0; mt < 4; mt++)
#pragma unroll
            for (int nt = 0; nt < 4; nt++) {
                acc[mt][nt] = MFMA16(af[mt][0], bfr[nt][0], acc[mt][nt]);
                acc[mt][nt] = MFMA16(af[mt][1], bfr[nt][1], acc[mt][nt]);
            }
    }

    float bv4[4];
#pragma unroll
    for (int nt = 0; nt < 4; nt++) bv4[nt] = bias[n0 + no + nt * 16 + l15];

    const int h = (n0 + no) >> 6;
    if (z == 2) {
        // transposed V epilogue: vt[bh][d][s]
#pragma unroll
        for (int mt = 0; mt < 4; mt++) {
            int m = m0 + mo + mt * 16 + lg * 4;       // 4-aligned, never crosses b
            int bb = m >> 11, s = m & (SS - 1);
#pragma unroll
            for (int nt = 0; nt < 4; nt++) {
                int d = nt * 16 + l15;
                bf16x4 pk;
#pragma unroll
                for (int r = 0; r < 4; r++) pk[r] = (short)f2bf(acc[mt][nt][r] + bv4[nt]);
                *(bf16x4*)(out + (((size_t)bb * HH + h) * DKK + d) * SS + s) = pk;
            }
        }
    } else {
#pragma unroll
        for (int mt = 0; mt < 4; mt++)
#pragma unroll
            for (int nt = 0; nt < 4; nt++)
#pragma unroll
                for (int r = 0; r < 4; r++) {
                    int m = m0 + mo + mt * 16 + lg * 4 + r;
                    int d = nt * 16 + l15;
                    float v = (acc[mt][nt][r] + bv4[nt]) * scale;
                    int bb = m >> 11, s = m & (SS - 1);
                    out[(((size_t)bb * HH + h) * SS + s) * 64 + d] = f2bf(v);
                }
    }
}

// ---------------------------------------------------------------------------
// Output projection: out[m][n] = sum_k A[m][k]*Wo[n][k] + bo[n]
// A bf16 [16384,512] (ws), Wo fp32 [512,512], out fp32 row-major (d_out).
// ---------------------------------------------------------------------------
__global__ __launch_bounds__(256, 2) void proj_out_mfma(
    const unsigned short* __restrict__ Xb,
    const float* __restrict__ W,
    const float* __restrict__ bias,
    float* __restrict__ out)
{
    __shared__ __align__(16) unsigned short Xs[128][72];
    __shared__ __align__(16) unsigned short Ws[128][72];
    const int t = threadIdx.x;
    const int w = t >> 6, l = t & 63;
    const int l15 = l & 15, lg = l >> 4;
    const int n0 = blockIdx.x * 128, m0 = blockIdx.y * 128;
    const int mo = (w & 1) * 64, no = (w >> 1) * 64;

    f32x4 acc[4][4];
#pragma unroll
    for (int i = 0; i < 4; i++)
#pragma unroll
        for (int j = 0; j < 4; j++) acc[i][j] = (f32x4){0.f, 0.f, 0.f, 0.f};

    for (int k0 = 0; k0 < DM; k0 += 64) {
        __syncthreads();
#pragma unroll
        for (int rr = 0; rr < 4; rr++) {
            int idx = rr * 2048 + t * 8;
            int row = idx >> 6, col = idx & 63;
            *(uint4*)&Xs[row][col] = *(const uint4*)(Xb + (size_t)(m0 + row) * DM + k0 + col);
            *(uint4*)&Ws[row][col] = cvt8(W + (size_t)(n0 + row) * DM + k0 + col);
        }
        __syncthreads();

        bf16x8 af[4][2], bfr[4][2];
#pragma unroll
        for (int mt = 0; mt < 4; mt++) {
            af[mt][0] = *(const bf16x8*)&Xs[mo + mt * 16 + l15][lg * 8];
            af[mt][1] = *(const bf16x8*)&Xs[mo + mt * 16 + l15][32 + lg * 8];
        }
#pragma unroll
        for (int nt = 0; nt < 4; nt++) {
            bfr[nt][0] = *(const bf16x8*)&Ws[no + nt * 16 + l15][lg * 8];
            bfr[nt][1] = *(const bf16x8*)&Ws[no + nt * 16 + l15][32 + lg * 8];
        }
#pragma unroll
        for (int mt = 0; mt < 4; mt++)
#pragma unroll
            for (int nt = 0; nt < 4; nt++) {
                acc[mt][nt] = MFMA16(af[mt][0], bfr[nt][0], acc[mt][nt]);
                acc[mt][nt] = MFMA16(af[mt][1], bfr[nt][1], acc[mt][nt]);
            }
    }

    float bv4[4];
#pragma unroll
    for (int nt = 0; nt < 4; nt++) bv4[nt] = bias[n0 + no + nt * 16 + l15];

#pragma unroll
    for (int mt = 0; mt < 4; mt++)
#pragma unroll
        for (int nt = 0; nt < 4; nt++)
#pragma unroll
            for (int r = 0; r < 4; r++) {
                int m = m0 + mo + mt * 16 + lg * 4 + r;
                int n = n0 + no + nt * 16 + l15;
                out[(size_t)m * DM + n] = acc[mt][nt][r] + bv4[nt];
            }
}

// ---------------------------------------------------------------------------
// Flash attention, bf16 MFMA. Block = (qblock of 256 rows) x (b,h).
// 4 waves; wave w owns q rows [w*64, w*64+64). kv tiles of 64.
// S^T = K·Q^T (C-layout packs 4 consecutive kv per lane -> packed 8B P-store).
// Softmax in exp2 domain (log2e folded into q).
// Mask: bit-packed uint64 words ([S][S/64]); bit=0 -> -1e38.
// Defer-max (THR=0, bit-exact): skip alpha/rescale when no row max grew.
// V comes pre-transposed ([bh][d][s]) -> Vt staged with uint4 copies.
// Pw: linear [4][64][64] + XOR swizzle (col^=(row&7)<<3 shorts) -> LDS
// 51200B -> 3 blocks/CU.
// ---------------------------------------------------------------------------
__global__ __launch_bounds__(256, 3) void attn_kernel(
    const unsigned short* __restrict__ qw, const unsigned short* __restrict__ kw,
    const unsigned short* __restrict__ vtw,
    const unsigned long long* __restrict__ mb,
    unsigned short* __restrict__ ao)   // [B,S,512] bf16
{
    __shared__ __align__(16) unsigned short Ks[64][72];   // [kv][d]
    __shared__ __align__(16) unsigned short Vt[64][72];   // [d][kv]
    __shared__ __align__(16) unsigned short Pw[4 * 64 * 64]; // per-wave [q][kv] swizzled
    const int t = threadIdx.x;
    const int w = t >> 6, l = t & 63;
    const int l15 = l & 15, lg = l >> 4;
    const int q0 = blockIdx.x * 256;
    const int bh = blockIdx.y;
    const int b = bh >> 3, h = bh & 7;
    const int q0w = q0 + w * 64;
    const unsigned short* qb = qw + (size_t)bh * SS * DKK;
    const unsigned short* kb = kw + (size_t)bh * SS * DKK;
    const unsigned short* vtb = vtw + (size_t)bh * DKK * SS;

    // Per-qt bit-mask row base (row = q0w + qt*16 + l15; 32 words per row)
    const unsigned long long* mbq[4];
#pragma unroll
    for (int qt = 0; qt < 4; qt++)
        mbq[qt] = mb + ((size_t)(q0w + qt * 16 + l15) << 5);

    // Q fragments (B-operand): Qf[qt][dh] = Q[q0w+qt*16+l15][dh*32+lg*8 ..+8]
    bf16x8 Qf[4][2];
#pragma unroll
    for (int qt = 0; qt < 4; qt++)
#pragma unroll
        for (int dh = 0; dh < 2; dh++)
            Qf[qt][dh] = *(const bf16x8*)(qb + (size_t)(q0w + qt * 16 + l15) * DKK + dh * 32 + lg * 8);

    f32x4 O[4][4];   // [qt][dt]: row q = qt*16+lg*4+r, col d = dt*16+l15
#pragma unroll
    for (int i = 0; i < 4; i++)
#pragma unroll
        for (int j = 0; j < 4; j++) O[i][j] = (f32x4){0.f, 0.f, 0.f, 0.f};
    float m_i[4], l_i[4];
#pragma unroll
    for (int i = 0; i < 4; i++) { m_i[i] = -INFINITY; l_i[i] = 0.f; }

    const int pbase = w * 4096;

    for (int kv0 = 0; kv0 < SS; kv0 += 64) {
        __syncthreads();   // all waves done with Ks/Vt of previous tile
        // ---- stage K tile + (pre-transposed) V tile, clean uint4 copies ----
#pragma unroll
        for (int r = 0; r < 2; r++) {
            int idx = r * 2048 + t * 8;
            int row = idx >> 6, col = idx & 63;
            *(uint4*)&Ks[row][col] = *(const uint4*)(kb + (size_t)(kv0 + row) * DKK + col);
            *(uint4*)&Vt[row][col] = *(const uint4*)(vtb + (size_t)row * SS + kv0 + col);
        }
        __syncthreads();

        // ---- S^T = K·Q^T : S[kvt][qt], row kv = kvt*16+lg*4+r, col q = qt*16+l15
        f32x4 S[4][4];
#pragma unroll
        for (int kvt = 0; kvt < 4; kvt++) {
            bf16x8 ak0 = *(const bf16x8*)&Ks[kvt * 16 + l15][lg * 8];
            bf16x8 ak1 = *(const bf16x8*)&Ks[kvt * 16 + l15][32 + lg * 8];
#pragma unroll
            for (int qt = 0; qt < 4; qt++) {
                f32x4 z = (f32x4){0.f, 0.f, 0.f, 0.f};
                z = MFMA16(ak0, Qf[qt][0], z);
                z = MFMA16(ak1, Qf[qt][1], z);
                S[kvt][qt] = z;
            }
        }

        // ---- mask via packed bits: bit kv_local = kvt*16 + lg*4 + r ----
#pragma unroll
        for (int qt = 0; qt < 4; qt++) {
            unsigned long long mm = mbq[qt][kv0 >> 6];
            unsigned int wlo = (unsigned int)mm;
            unsigned int whi = (unsigned int)(mm >> 32);
            unsigned int u[4];
            u[0] = wlo >> (lg * 4);
            u[1] = wlo >> (16 + lg * 4);
            u[2] = whi >> (lg * 4);
            u[3] = whi >> (16 + lg * 4);
#pragma unroll
            for (int kvt = 0; kvt < 4; kvt++) {
                if (!(u[kvt] & 1u)) S[kvt][qt][0] = -1e38f;
                if (!(u[kvt] & 2u)) S[kvt][qt][1] = -1e38f;
                if (!(u[kvt] & 4u)) S[kvt][qt][2] = -1e38f;
                if (!(u[kvt] & 8u)) S[kvt][qt][3] = -1e38f;
            }
        }

        // ---- online softmax (exp2 domain) with defer-max (THR=0) ----
        float mtl[4];
#pragma unroll
        for (int qt = 0; qt < 4; qt++) {
            float mt = S[0][qt][0];
#pragma unroll
            for (int kvt = 0; kvt < 4; kvt++)
#pragma unroll
                for (int r = 0; r < 4; r++) mt = fmaxf(mt, S[kvt][qt][r]);
            mt = fmaxf(mt, __shfl_xor(mt, 16));
            mt = fmaxf(mt, __shfl_xor(mt, 32));
            mtl[qt] = mt;
        }
        int grow = (mtl[0] > m_i[0]) | (mtl[1] > m_i[1]) |
                   (mtl[2] > m_i[2]) | (mtl[3] > m_i[3]);
        if (__any(grow)) {
            float alpha[4];
#pragma unroll
            for (int qt = 0; qt < 4; qt++) {
                float mn = fmaxf(m_i[qt], mtl[qt]);
                alpha[qt] = EXP2(m_i[qt] - mn);
                m_i[qt] = mn;
                l_i[qt] *= alpha[qt];
            }
            // rescale O by alpha (broadcast from q-col lanes to q-row regs)
#pragma unroll
            for (int qt = 0; qt < 4; qt++)
#pragma unroll
                for (int r = 0; r < 4; r++) {
                    float a = __shfl(alpha[qt], lg * 4 + r);
#pragma unroll
                    for (int dt = 0; dt < 4; dt++) O[qt][dt][r] *= a;
                }
        }

#pragma unroll
        for (int qt = 0; qt < 4; qt++) {
            float ls = 0.f;
            const int prow = qt * 16 + l15;
            const int swz = (prow & 7) << 3;
#pragma unroll
            for (int kvt = 0; kvt < 4; kvt++) {
                float p0 = EXP2(S[kvt][qt][0] - m_i[qt]);
                float p1 = EXP2(S[kvt][qt][1] - m_i[qt]);
                float p2 = EXP2(S[kvt][qt][2] - m_i[qt]);
                float p3 = EXP2(S[kvt][qt][3] - m_i[qt]);
                ls += (p0 + p1) + (p2 + p3);
                bf16x4 pk;
                pk[0] = (short)f2bf(p0); pk[1] = (short)f2bf(p1);
                pk[2] = (short)f2bf(p2); pk[3] = (short)f2bf(p3);
                *(bf16x4*)&Pw[pbase + prow * 64 + ((kvt * 16 + lg * 4) ^ swz)] = pk;
            }
            ls += __shfl_xor(ls, 16);
            ls += __shfl_xor(ls, 32);
            l_i[qt] += ls;
        }

        // Pw is wave-private: per-wave DS ops complete in order, so a block
        // barrier is unnecessary. The fence stops the compiler from hoisting
        // the ap reads above the pk stores.
        asm volatile("s_waitcnt lgkmcnt(0)" ::: "memory");

        // ---- O += P·V ----
        bf16x8 bv2[4][2];
#pragma unroll
        for (int dt = 0; dt < 4; dt++) {
            bv2[dt][0] = *(const bf16x8*)&Vt[dt * 16 + l15][lg * 8];
            bv2[dt][1] = *(const bf16x8*)&Vt[dt * 16 + l15][32 + lg * 8];
        }
#pragma unroll
        for (int qt = 0; qt < 4; qt++) {
            const int prow = qt * 16 + l15;
            const int swz = (prow & 7) << 3;
            bf16x8 ap0 = *(const bf16x8*)&Pw[pbase + prow * 64 + ((lg * 8) ^ swz)];
            bf16x8 ap1 = *(const bf16x8*)&Pw[pbase + prow * 64 + ((32 + lg * 8) ^ swz)];
#pragma unroll
            for (int dt = 0; dt < 4; dt++) {
                O[qt][dt] = MFMA16(ap0, bv2[dt][0], O[qt][dt]);
                O[qt][dt] = MFMA16(ap1, bv2[dt][1], O[qt][dt]);
            }
        }
    }

    // ---- epilogue: normalize by l, store bf16 to [b][s][h*64+d] ----
#pragma unroll
    for (int qt = 0; qt < 4; qt++) {
        float li = 1.f / l_i[qt];
#pragma unroll
        for (int r = 0; r < 4; r++) {
            float lv = __shfl(li, lg * 4 + r);
            int q = q0w + qt * 16 + lg * 4 + r;
            size_t base = ((size_t)b * SS + q) * DM + h * 64;
#pragma unroll
            for (int dt = 0; dt < 4; dt++)
                ao[base + dt * 16 + l15] = f2bf(O[qt][dt][r] * lv);
        }
    }
}

extern "C" void kernel_launch(void* const* d_in, const int* in_sizes, int n_in,
                              void* d_out, int out_size, void* d_ws, size_t ws_size,
                              hipStream_t stream) {
    // All float tensors are fp32 (proven). mask is int32.
    const float* Q    = (const float*)d_in[0];
    const float* K    = (const float*)d_in[1];
    const float* V    = (const float*)d_in[2];
    const int*   mask = (const int*)d_in[3];
    const float* Wq   = (const float*)d_in[4];
    const float* bq   = (const float*)d_in[5];
    const float* Wk   = (const float*)d_in[6];
    const float* bk   = (const float*)d_in[7];
    const float* Wv   = (const float*)d_in[8];
    const float* bv   = (const float*)d_in[9];
    const float* Wo   = (const float*)d_in[10];
    const float* bo   = (const float*)d_in[11];

    // ws: [qb 16 MB][kb 16 MB][vtb 16 MB][ab 16 MB] = 64 MB (proven-safe).
    // vtb holds V ALREADY TRANSPOSED ([bh][64][S]) — written directly by
    // proj_qkv_fused's z==2 epilogue. No scratch in d_out except the mask
    // tail (round-1-proven placement; nothing else touches d_out before
    // attn reads it).
    const size_t SEG = (size_t)BB * HH * SS * DKK;  // 8,388,608 bf16 elems
    unsigned short* qb  = (unsigned short*)d_ws;
    unsigned short* kb  = qb + SEG;
    unsigned short* vtb = kb + SEG;
    unsigned short* ab  = vtb + SEG;

    const size_t MB_BYTES = (size_t)SS * (SS / 64) * sizeof(unsigned long long); // 524288
    unsigned long long* mbits =
        (unsigned long long*)((char*)d_out + (size_t)out_size - MB_BYTES);

    const float qscale = 0.125f * 1.44269504088896340736f;  // 1/sqrt(dk) * log2(e)

    // words = S*(S/64) = 65536; 4 waves (one word each) per 256-thread block
    mask_pack<<<dim3((SS * (SS / 64)) / 4), 256, 0, stream>>>(mask, mbits);

    dim3 gp(DM / 128, (BB * SS) / 128, 3);  // (4, 128, 3)
    proj_qkv_fused<<<gp, 256, 0, stream>>>(Q, K, V, Wq, Wk, Wv, bq, bk, bv, qb, qscale);

    attn_kernel<<<dim3(SS / 256, BB * HH), 256, 0, stream>>>(qb, kb, vtb, mbits, ab);

    proj_out_mfma<<<dim3(DM / 128, (BB * SS) / 128), 256, 0, stream>>>(ab, Wo, bo, (float*)d_out);
}

// Round 4
// 407.763 us; speedup vs baseline: 1.7655x; 1.7655x over previous
//
#include <hip/hip_runtime.h>
#include <hip/hip_bf16.h>
#include <math.h>

#define BB 8
#define SS 2048
#define HH 8
#define DKK 64
#define DM 512

typedef short bf16x8 __attribute__((ext_vector_type(8)));
typedef short bf16x4 __attribute__((ext_vector_type(4)));
typedef float f32x4 __attribute__((ext_vector_type(4)));
#define MFMA16(a, b, c) __builtin_amdgcn_mfma_f32_16x16x32_bf16(a, b, c, 0, 0, 0)

#if __has_builtin(__builtin_amdgcn_exp2f)
#define EXP2(x) __builtin_amdgcn_exp2f(x)
#else
#define EXP2(x) exp2f(x)
#endif

__device__ __forceinline__ unsigned short f2bf(float f) {
    __hip_bfloat16 h = __float2bfloat16(f);
    return *reinterpret_cast<unsigned short*>(&h);
}

// Convert 8 consecutive fp32 -> 8 bf16, return as uint4 for a 16B LDS store.
__device__ __forceinline__ uint4 cvt8(const float* __restrict__ src) {
    float4 a = *(const float4*)src;
    float4 b = *(const float4*)(src + 4);
    unsigned short tmp[8];
    tmp[0] = f2bf(a.x); tmp[1] = f2bf(a.y); tmp[2] = f2bf(a.z); tmp[3] = f2bf(a.w);
    tmp[4] = f2bf(b.x); tmp[5] = f2bf(b.y); tmp[6] = f2bf(b.z); tmp[7] = f2bf(b.w);
    return *(uint4*)tmp;
}

// ---------------------------------------------------------------------------
// Mask bit-pack: mask int32 [S][S] -> mb uint64 [S][S/64], bit i of word
// (q, c) = (mask[q][c*64+i] != 0). One wave per output word via __ballot.
// ---------------------------------------------------------------------------
__global__ __launch_bounds__(256) void mask_pack(
    const int* __restrict__ mask, unsigned long long* __restrict__ mb)
{
    const int t = threadIdx.x;
    const int wid = (blockIdx.x << 2) | (t >> 6);   // global wave id == word idx
    const int lane = t & 63;
    const int q = wid >> 5;          // / (SS/64)
    const int c = wid & 31;
    int e = mask[(size_t)q * SS + (c << 6) + lane];
    unsigned long long bal = __ballot(e != 0);
    if (lane == 0) mb[wid] = bal;
}

// ---------------------------------------------------------------------------
// Fused QKV projection (gridDim.z selects Q/K/V): out[m][n] =
// (sum_k X[m][k]*W[n][k] + bias[n]) * scale. Internals identical to the
// proven proj_qkv_mfma for the K-loop.
// z=0 (Q), z=1 (K): out bf16 scattered to [B*H][S][64] (n = h*64+d).
// z=2 (V): out written TRANSPOSED to [B*H][64][S] (so attn can stage the
//          V tile with clean uint4 copies). bf16x4 stores (4 consecutive s).
// ---------------------------------------------------------------------------
__global__ __launch_bounds__(256, 2) void proj_qkv_fused(
    const float* __restrict__ Xq, const float* __restrict__ Xk, const float* __restrict__ Xv,
    const float* __restrict__ Wq, const float* __restrict__ Wk, const float* __restrict__ Wv,
    const float* __restrict__ bq, const float* __restrict__ bk, const float* __restrict__ bv,
    unsigned short* __restrict__ outbase, float qscale)
{
    const int z = blockIdx.z;
    const float* X = (z == 0) ? Xq : (z == 1) ? Xk : Xv;
    const float* W = (z == 0) ? Wq : (z == 1) ? Wk : Wv;
    const float* bias = (z == 0) ? bq : (z == 1) ? bk : bv;
    unsigned short* out = outbase + (size_t)z * ((size_t)BB * HH * SS * DKK);
    const float scale = (z == 0) ? qscale : 1.0f;

    __shared__ __align__(16) unsigned short Xs[128][72];
    __shared__ __align__(16) unsigned short Ws[128][72];
    const int t = threadIdx.x;
    const int w = t >> 6, l = t & 63;
    const int l15 = l & 15, lg = l >> 4;
    const int n0 = blockIdx.x * 128, m0 = blockIdx.y * 128;
    const int mo = (w & 1) * 64, no = (w >> 1) * 64;

    f32x4 acc[4][4];
#pragma unroll
    for (int i = 0; i < 4; i++)
#pragma unroll
        for (int j = 0; j < 4; j++) acc[i][j] = (f32x4){0.f, 0.f, 0.f, 0.f};

    for (int k0 = 0; k0 < DM; k0 += 64) {
        __syncthreads();
#pragma unroll
        for (int rr = 0; rr < 4; rr++) {
            int idx = rr * 2048 + t * 8;
            int row = idx >> 6, col = idx & 63;
            *(uint4*)&Xs[row][col] = cvt8(X + (size_t)(m0 + row) * DM + k0 + col);
            *(uint4*)&Ws[row][col] = cvt8(W + (size_t)(n0 + row) * DM + k0 + col);
        }
        __syncthreads();

        bf16x8 af[4][2], bfr[4][2];
#pragma unroll
        for (int mt = 0; mt < 4; mt++) {
            af[mt][0] = *(const bf16x8*)&Xs[mo + mt * 16 + l15][lg * 8];
            af[mt][1] = *(const bf16x8*)&Xs[mo + mt * 16 + l15][32 + lg * 8];
        }
#pragma unroll
        for (int nt = 0; nt < 4; nt++) {
            bfr[nt][0] = *(const bf16x8*)&Ws[no + nt * 16 + l15][lg * 8];
            bfr[nt][1] = *(const bf16x8*)&Ws[no + nt * 16 + l15][32 + lg * 8];
        }
#pragma unroll
        for (int mt = 0; mt < 4; mt++)
#pragma unroll
            for (int nt = 0; nt < 4; nt++) {
                acc[mt][nt] = MFMA16(af[mt][0], bfr[nt][0], acc[mt][nt]);
                acc[mt][nt] = MFMA16(af[mt][1], bfr[nt][1], acc[mt][nt]);
            }
    }

    float bv4[4];
#pragma unroll
    for (int nt = 0; nt < 4; nt++) bv4[nt] = bias[n0 + no + nt * 16 + l15];

    const int h = (n0 + no) >> 6;
    if (z == 2) {
        // transposed V epilogue: vt[bh][d][s]
#pragma unroll
        for (int mt = 0; mt < 4; mt++) {
            int m = m0 + mo + mt * 16 + lg * 4;       // 4-aligned, never crosses b
            int bb = m >> 11, s = m & (SS - 1);
#pragma unroll
            for (int nt = 0; nt < 4; nt++) {
                int d = nt * 16 + l15;
                bf16x4 pk;
#pragma unroll
                for (int r = 0; r < 4; r++) pk[r] = (short)f2bf(acc[mt][nt][r] + bv4[nt]);
                *(bf16x4*)(out + (((size_t)bb * HH + h) * DKK + d) * SS + s) = pk;
            }
        }
    } else {
#pragma unroll
        for (int mt = 0; mt < 4; mt++)
#pragma unroll
            for (int nt = 0; nt < 4; nt++)
#pragma unroll
                for (int r = 0; r < 4; r++) {
                    int m = m0 + mo + mt * 16 + lg * 4 + r;
                    int d = nt * 16 + l15;
                    float v = (acc[mt][nt][r] + bv4[nt]) * scale;
                    int bb = m >> 11, s = m & (SS - 1);
                    out[(((size_t)bb * HH + h) * SS + s) * 64 + d] = f2bf(v);
                }
    }
}

// ---------------------------------------------------------------------------
// Output projection: out[m][n] = sum_k A[m][k]*Wo[n][k] + bo[n]
// A bf16 [16384,512] (ws), Wo fp32 [512,512], out fp32 row-major (d_out).
// ---------------------------------------------------------------------------
__global__ __launch_bounds__(256, 2) void proj_out_mfma(
    const unsigned short* __restrict__ Xb,
    const float* __restrict__ W,
    const float* __restrict__ bias,
    float* __restrict__ out)
{
    __shared__ __align__(16) unsigned short Xs[128][72];
    __shared__ __align__(16) unsigned short Ws[128][72];
    const int t = threadIdx.x;
    const int w = t >> 6, l = t & 63;
    const int l15 = l & 15, lg = l >> 4;
    const int n0 = blockIdx.x * 128, m0 = blockIdx.y * 128;
    const int mo = (w & 1) * 64, no = (w >> 1) * 64;

    f32x4 acc[4][4];
#pragma unroll
    for (int i = 0; i < 4; i++)
#pragma unroll
        for (int j = 0; j < 4; j++) acc[i][j] = (f32x4){0.f, 0.f, 0.f, 0.f};

    for (int k0 = 0; k0 < DM; k0 += 64) {
        __syncthreads();
#pragma unroll
        for (int rr = 0; rr < 4; rr++) {
            int idx = rr * 2048 + t * 8;
            int row = idx >> 6, col = idx & 63;
            *(uint4*)&Xs[row][col] = *(const uint4*)(Xb + (size_t)(m0 + row) * DM + k0 + col);
            *(uint4*)&Ws[row][col] = cvt8(W + (size_t)(n0 + row) * DM + k0 + col);
        }
        __syncthreads();

        bf16x8 af[4][2], bfr[4][2];
#pragma unroll
        for (int mt = 0; mt < 4; mt++) {
            af[mt][0] = *(const bf16x8*)&Xs[mo + mt * 16 + l15][lg * 8];
            af[mt][1] = *(const bf16x8*)&Xs[mo + mt * 16 + l15][32 + lg * 8];
        }
#pragma unroll
        for (int nt = 0; nt < 4; nt++) {
            bfr[nt][0] = *(const bf16x8*)&Ws[no + nt * 16 + l15][lg * 8];
            bfr[nt][1] = *(const bf16x8*)&Ws[no + nt * 16 + l15][32 + lg * 8];
        }
#pragma unroll
        for (int mt = 0; mt < 4; mt++)
#pragma unroll
            for (int nt = 0; nt < 4; nt++) {
                acc[mt][nt] = MFMA16(af[mt][0], bfr[nt][0], acc[mt][nt]);
                acc[mt][nt] = MFMA16(af[mt][1], bfr[nt][1], acc[mt][nt]);
            }
    }

    float bv4[4];
#pragma unroll
    for (int nt = 0; nt < 4; nt++) bv4[nt] = bias[n0 + no + nt * 16 + l15];

#pragma unroll
    for (int mt = 0; mt < 4; mt++)
#pragma unroll
        for (int nt = 0; nt < 4; nt++)
#pragma unroll
            for (int r = 0; r < 4; r++) {
                int m = m0 + mo + mt * 16 + lg * 4 + r;
                int n = n0 + no + nt * 16 + l15;
                out[(size_t)m * DM + n] = acc[mt][nt][r] + bv4[nt];
            }
}

// ---------------------------------------------------------------------------
// Flash attention, bf16 MFMA. Block = (qblock of 256 rows) x (b,h).
// 4 waves; wave w owns q rows [w*64, w*64+64). kv tiles of 64.
// S^T = K·Q^T (C-layout packs 4 consecutive kv per lane -> packed 8B P-store).
// Softmax in exp2 domain (log2e folded into q).
// Mask: bit-packed uint64 words ([S][S/64]); bit=0 -> -1e38.
// Defer-max (THR=0, bit-exact): skip alpha/rescale when no row max grew.
// V comes pre-transposed ([bh][d][s]) -> Vt staged with uint4 copies.
// Pw: linear [4][64][64] + XOR swizzle (col^=(row&7)<<3 shorts) -> LDS 51200B.
// __launch_bounds__(256,2): (256,3) made the allocator spill the O
// accumulator to scratch (VGPR 128->84, +1.4 GB HBM spill traffic, round 3).
// At 128 VGPR the real occupancy is LDS-limited at 3 blocks/CU anyway.
// ---------------------------------------------------------------------------
__global__ __launch_bounds__(256, 2) void attn_kernel(
    const unsigned short* __restrict__ qw, const unsigned short* __restrict__ kw,
    const unsigned short* __restrict__ vtw,
    const unsigned long long* __restrict__ mb,
    unsigned short* __restrict__ ao)   // [B,S,512] bf16
{
    __shared__ __align__(16) unsigned short Ks[64][72];   // [kv][d]
    __shared__ __align__(16) unsigned short Vt[64][72];   // [d][kv]
    __shared__ __align__(16) unsigned short Pw[4 * 64 * 64]; // per-wave [q][kv] swizzled
    const int t = threadIdx.x;
    const int w = t >> 6, l = t & 63;
    const int l15 = l & 15, lg = l >> 4;
    const int q0 = blockIdx.x * 256;
    const int bh = blockIdx.y;
    const int b = bh >> 3, h = bh & 7;
    const int q0w = q0 + w * 64;
    const unsigned short* qb = qw + (size_t)bh * SS * DKK;
    const unsigned short* kb = kw + (size_t)bh * SS * DKK;
    const unsigned short* vtb = vtw + (size_t)bh * DKK * SS;

    // Per-qt bit-mask row base (row = q0w + qt*16 + l15; 32 words per row)
    const unsigned long long* mbq[4];
#pragma unroll
    for (int qt = 0; qt < 4; qt++)
        mbq[qt] = mb + ((size_t)(q0w + qt * 16 + l15) << 5);

    // Q fragments (B-operand): Qf[qt][dh] = Q[q0w+qt*16+l15][dh*32+lg*8 ..+8]
    bf16x8 Qf[4][2];
#pragma unroll
    for (int qt = 0; qt < 4; qt++)
#pragma unroll
        for (int dh = 0; dh < 2; dh++)
            Qf[qt][dh] = *(const bf16x8*)(qb + (size_t)(q0w + qt * 16 + l15) * DKK + dh * 32 + lg * 8);

    f32x4 O[4][4];   // [qt][dt]: row q = qt*16+lg*4+r, col d = dt*16+l15
#pragma unroll
    for (int i = 0; i < 4; i++)
#pragma unroll
        for (int j = 0; j < 4; j++) O[i][j] = (f32x4){0.f, 0.f, 0.f, 0.f};
    float m_i[4], l_i[4];
#pragma unroll
    for (int i = 0; i < 4; i++) { m_i[i] = -INFINITY; l_i[i] = 0.f; }

    const int pbase = w * 4096;

    for (int kv0 = 0; kv0 < SS; kv0 += 64) {
        __syncthreads();   // all waves done with Ks/Vt of previous tile
        // ---- stage K tile + (pre-transposed) V tile, clean uint4 copies ----
#pragma unroll
        for (int r = 0; r < 2; r++) {
            int idx = r * 2048 + t * 8;
            int row = idx >> 6, col = idx & 63;
            *(uint4*)&Ks[row][col] = *(const uint4*)(kb + (size_t)(kv0 + row) * DKK + col);
            *(uint4*)&Vt[row][col] = *(const uint4*)(vtb + (size_t)row * SS + kv0 + col);
        }
        __syncthreads();

        // ---- S^T = K·Q^T : S[kvt][qt], row kv = kvt*16+lg*4+r, col q = qt*16+l15
        f32x4 S[4][4];
#pragma unroll
        for (int kvt = 0; kvt < 4; kvt++) {
            bf16x8 ak0 = *(const bf16x8*)&Ks[kvt * 16 + l15][lg * 8];
            bf16x8 ak1 = *(const bf16x8*)&Ks[kvt * 16 + l15][32 + lg * 8];
#pragma unroll
            for (int qt = 0; qt < 4; qt++) {
                f32x4 z = (f32x4){0.f, 0.f, 0.f, 0.f};
                z = MFMA16(ak0, Qf[qt][0], z);
                z = MFMA16(ak1, Qf[qt][1], z);
                S[kvt][qt] = z;
            }
        }

        // ---- mask via packed bits: bit kv_local = kvt*16 + lg*4 + r ----
#pragma unroll
        for (int qt = 0; qt < 4; qt++) {
            unsigned long long mm = mbq[qt][kv0 >> 6];
            unsigned int wlo = (unsigned int)mm;
            unsigned int whi = (unsigned int)(mm >> 32);
            unsigned int u[4];
            u[0] = wlo >> (lg * 4);
            u[1] = wlo >> (16 + lg * 4);
            u[2] = whi >> (lg * 4);
            u[3] = whi >> (16 + lg * 4);
#pragma unroll
            for (int kvt = 0; kvt < 4; kvt++) {
                if (!(u[kvt] & 1u)) S[kvt][qt][0] = -1e38f;
                if (!(u[kvt] & 2u)) S[kvt][qt][1] = -1e38f;
                if (!(u[kvt] & 4u)) S[kvt][qt][2] = -1e38f;
                if (!(u[kvt] & 8u)) S[kvt][qt][3] = -1e38f;
            }
        }

        // ---- online softmax (exp2 domain) with defer-max (THR=0) ----
        float mtl[4];
#pragma unroll
        for (int qt = 0; qt < 4; qt++) {
            float mt = S[0][qt][0];
#pragma unroll
            for (int kvt = 0; kvt < 4; kvt++)
#pragma unroll
                for (int r = 0; r < 4; r++) mt = fmaxf(mt, S[kvt][qt][r]);
            mt = fmaxf(mt, __shfl_xor(mt, 16));
            mt = fmaxf(mt, __shfl_xor(mt, 32));
            mtl[qt] = mt;
        }
        int grow = (mtl[0] > m_i[0]) | (mtl[1] > m_i[1]) |
                   (mtl[2] > m_i[2]) | (mtl[3] > m_i[3]);
        if (__any(grow)) {
            float alpha[4];
#pragma unroll
            for (int qt = 0; qt < 4; qt++) {
                float mn = fmaxf(m_i[qt], mtl[qt]);
                alpha[qt] = EXP2(m_i[qt] - mn);
                m_i[qt] = mn;
                l_i[qt] *= alpha[qt];
            }
            // rescale O by alpha (broadcast from q-col lanes to q-row regs)
#pragma unroll
            for (int qt = 0; qt < 4; qt++)
#pragma unroll
                for (int r = 0; r < 4; r++) {
                    float a = __shfl(alpha[qt], lg * 4 + r);
#pragma unroll
                    for (int dt = 0; dt < 4; dt++) O[qt][dt][r] *= a;
                }
        }

#pragma unroll
        for (int qt = 0; qt < 4; qt++) {
            float ls = 0.f;
            const int prow = qt * 16 + l15;
            const int swz = (prow & 7) << 3;
#pragma unroll
            for (int kvt = 0; kvt < 4; kvt++) {
                float p0 = EXP2(S[kvt][qt][0] - m_i[qt]);
                float p1 = EXP2(S[kvt][qt][1] - m_i[qt]);
                float p2 = EXP2(S[kvt][qt][2] - m_i[qt]);
                float p3 = EXP2(S[kvt][qt][3] - m_i[qt]);
                ls += (p0 + p1) + (p2 + p3);
                bf16x4 pk;
                pk[0] = (short)f2bf(p0); pk[1] = (short)f2bf(p1);
                pk[2] = (short)f2bf(p2); pk[3] = (short)f2bf(p3);
                *(bf16x4*)&Pw[pbase + prow * 64 + ((kvt * 16 + lg * 4) ^ swz)] = pk;
            }
            ls += __shfl_xor(ls, 16);
            ls += __shfl_xor(ls, 32);
            l_i[qt] += ls;
        }

        // Pw is wave-private: per-wave DS ops complete in order, so a block
        // barrier is unnecessary. The fence stops the compiler from hoisting
        // the ap reads above the pk stores.
        asm volatile("s_waitcnt lgkmcnt(0)" ::: "memory");

        // ---- O += P·V ----
        bf16x8 bv2[4][2];
#pragma unroll
        for (int dt = 0; dt < 4; dt++) {
            bv2[dt][0] = *(const bf16x8*)&Vt[dt * 16 + l15][lg * 8];
            bv2[dt][1] = *(const bf16x8*)&Vt[dt * 16 + l15][32 + lg * 8];
        }
#pragma unroll
        for (int qt = 0; qt < 4; qt++) {
            const int prow = qt * 16 + l15;
            const int swz = (prow & 7) << 3;
            bf16x8 ap0 = *(const bf16x8*)&Pw[pbase + prow * 64 + ((lg * 8) ^ swz)];
            bf16x8 ap1 = *(const bf16x8*)&Pw[pbase + prow * 64 + ((32 + lg * 8) ^ swz)];
#pragma unroll
            for (int dt = 0; dt < 4; dt++) {
                O[qt][dt] = MFMA16(ap0, bv2[dt][0], O[qt][dt]);
                O[qt][dt] = MFMA16(ap1, bv2[dt][1], O[qt][dt]);
            }
        }
    }

    // ---- epilogue: normalize by l, store bf16 to [b][s][h*64+d] ----
#pragma unroll
    for (int qt = 0; qt < 4; qt++) {
        float li = 1.f / l_i[qt];
#pragma unroll
        for (int r = 0; r < 4; r++) {
            float lv = __shfl(li, lg * 4 + r);
            int q = q0w + qt * 16 + lg * 4 + r;
            size_t base = ((size_t)b * SS + q) * DM + h * 64;
#pragma unroll
            for (int dt = 0; dt < 4; dt++)
                ao[base + dt * 16 + l15] = f2bf(O[qt][dt][r] * lv);
        }
    }
}

extern "C" void kernel_launch(void* const* d_in, const int* in_sizes, int n_in,
                              void* d_out, int out_size, void* d_ws, size_t ws_size,
                              hipStream_t stream) {
    // All float tensors are fp32 (proven). mask is int32.
    const float* Q    = (const float*)d_in[0];
    const float* K    = (const float*)d_in[1];
    const float* V    = (const float*)d_in[2];
    const int*   mask = (const int*)d_in[3];
    const float* Wq   = (const float*)d_in[4];
    const float* bq   = (const float*)d_in[5];
    const float* Wk   = (const float*)d_in[6];
    const float* bk   = (const float*)d_in[7];
    const float* Wv   = (const float*)d_in[8];
    const float* bv   = (const float*)d_in[9];
    const float* Wo   = (const float*)d_in[10];
    const float* bo   = (const float*)d_in[11];

    // ws: [qb 16 MB][kb 16 MB][vtb 16 MB][ab 16 MB] = 64 MB (proven-safe).
    // vtb holds V ALREADY TRANSPOSED ([bh][64][S]) — written directly by
    // proj_qkv_fused's z==2 epilogue. No scratch in d_out except the mask
    // tail (round-1-proven placement).
    const size_t SEG = (size_t)BB * HH * SS * DKK;  // 8,388,608 bf16 elems
    unsigned short* qb  = (unsigned short*)d_ws;
    unsigned short* kb  = qb + SEG;
    unsigned short* vtb = kb + SEG;
    unsigned short* ab  = vtb + SEG;

    const size_t MB_BYTES = (size_t)SS * (SS / 64) * sizeof(unsigned long long); // 524288
    unsigned long long* mbits =
        (unsigned long long*)((char*)d_out + (size_t)out_size - MB_BYTES);

    const float qscale = 0.125f * 1.44269504088896340736f;  // 1/sqrt(dk) * log2(e)

    // words = S*(S/64) = 65536; 4 waves (one word each) per 256-thread block
    mask_pack<<<dim3((SS * (SS / 64)) / 4), 256, 0, stream>>>(mask, mbits);

    dim3 gp(DM / 128, (BB * SS) / 128, 3);  // (4, 128, 3)
    proj_qkv_fused<<<gp, 256, 0, stream>>>(Q, K, V, Wq, Wk, Wv, bq, bk, bv, qb, qscale);

    attn_kernel<<<dim3(SS / 256, BB * HH), 256, 0, stream>>>(qb, kb, vtb, mbits, ab);

    proj_out_mfma<<<dim3(DM / 128, (BB * SS) / 128), 256, 0, stream>>>(ab, Wo, bo, (float*)d_out);
}

// Round 5
// 392.646 us; speedup vs baseline: 1.8335x; 1.0385x over previous
//
#include <hip/hip_runtime.h>
#include <hip/hip_bf16.h>
#include <math.h>

#define BB 8
#define SS 2048
#define HH 8
#define DKK 64
#define DM 512

typedef short bf16x8 __attribute__((ext_vector_type(8)));
typedef short bf16x4 __attribute__((ext_vector_type(4)));
typedef float f32x4 __attribute__((ext_vector_type(4)));
#define MFMA16(a, b, c) __builtin_amdgcn_mfma_f32_16x16x32_bf16(a, b, c, 0, 0, 0)

#if __has_builtin(__builtin_amdgcn_exp2f)
#define EXP2(x) __builtin_amdgcn_exp2f(x)
#else
#define EXP2(x) exp2f(x)
#endif

__device__ __forceinline__ unsigned short f2bf(float f) {
    __hip_bfloat16 h = __float2bfloat16(f);
    return *reinterpret_cast<unsigned short*>(&h);
}

__device__ __forceinline__ float max3f(float a, float b, float c) {
    return fmaxf(fmaxf(a, b), c);   // clang fuses to v_max3_f32
}

// Convert 8 consecutive fp32 -> 8 bf16, return as uint4 for a 16B LDS store.
__device__ __forceinline__ uint4 cvt8(const float* __restrict__ src) {
    float4 a = *(const float4*)src;
    float4 b = *(const float4*)(src + 4);
    unsigned short tmp[8];
    tmp[0] = f2bf(a.x); tmp[1] = f2bf(a.y); tmp[2] = f2bf(a.z); tmp[3] = f2bf(a.w);
    tmp[4] = f2bf(b.x); tmp[5] = f2bf(b.y); tmp[6] = f2bf(b.z); tmp[7] = f2bf(b.w);
    return *(uint4*)tmp;
}

// ---------------------------------------------------------------------------
// Mask bit-pack: mask int32 [S][S] -> mb uint64 [S][S/64], bit i of word
// (q, c) = (mask[q][c*64+i] != 0). One wave per output word via __ballot.
// ---------------------------------------------------------------------------
__global__ __launch_bounds__(256) void mask_pack(
    const int* __restrict__ mask, unsigned long long* __restrict__ mb)
{
    const int t = threadIdx.x;
    const int wid = (blockIdx.x << 2) | (t >> 6);   // global wave id == word idx
    const int lane = t & 63;
    const int q = wid >> 5;          // / (SS/64)
    const int c = wid & 31;
    int e = mask[(size_t)q * SS + (c << 6) + lane];
    unsigned long long bal = __ballot(e != 0);
    if (lane == 0) mb[wid] = bal;
}

// ---------------------------------------------------------------------------
// W pre-convert: Wq/Wk/Wv fp32 [512][512] -> bf16, same layout, packed into
// dst (3 x 262144 elems = 1.5 MB). Removes the per-block-redundant cvt8 of
// W during proj staging (W was converted 128x redundantly).
// ---------------------------------------------------------------------------
__global__ __launch_bounds__(256) void w_cvt(
    const float* __restrict__ Wq, const float* __restrict__ Wk,
    const float* __restrict__ Wv, unsigned short* __restrict__ dst)
{
    const int idx = blockIdx.x * 256 + threadIdx.x;   // 0..98303
    const int which = idx >> 15;                       // / 32768
    const int off = (idx & 32767) * 8;
    const float* src = (which == 0) ? Wq : (which == 1) ? Wk : Wv;
    *(uint4*)(dst + (size_t)which * 262144 + off) = cvt8(src + off);
}

// ---------------------------------------------------------------------------
// Fused QKV projection (gridDim.z selects Q/K/V): out[m][n] =
// (sum_k X[m][k]*W[n][k] + bias[n]) * scale. W comes PRE-CONVERTED bf16
// (uint4-copy staging); X is fp32 (cvt8 staging).
// z=0 (Q), z=1 (K): out bf16 scattered to [B*H][S][64] (n = h*64+d).
// z=2 (V): out written TRANSPOSED to [B*H][64][S].
// ---------------------------------------------------------------------------
__global__ __launch_bounds__(256, 2) void proj_qkv_fused(
    const float* __restrict__ Xq, const float* __restrict__ Xk, const float* __restrict__ Xv,
    const unsigned short* __restrict__ Wb,
    const float* __restrict__ bq, const float* __restrict__ bk, const float* __restrict__ bv,
    unsigned short* __restrict__ outbase, float qscale)
{
    const int z = blockIdx.z;
    const float* X = (z == 0) ? Xq : (z == 1) ? Xk : Xv;
    const unsigned short* W = Wb + (size_t)z * 262144;
    const float* bias = (z == 0) ? bq : (z == 1) ? bk : bv;
    unsigned short* out = outbase + (size_t)z * ((size_t)BB * HH * SS * DKK);
    const float scale = (z == 0) ? qscale : 1.0f;

    __shared__ __align__(16) unsigned short Xs[128][72];
    __shared__ __align__(16) unsigned short Ws[128][72];
    const int t = threadIdx.x;
    const int w = t >> 6, l = t & 63;
    const int l15 = l & 15, lg = l >> 4;
    const int n0 = blockIdx.x * 128, m0 = blockIdx.y * 128;
    const int mo = (w & 1) * 64, no = (w >> 1) * 64;

    f32x4 acc[4][4];
#pragma unroll
    for (int i = 0; i < 4; i++)
#pragma unroll
        for (int j = 0; j < 4; j++) acc[i][j] = (f32x4){0.f, 0.f, 0.f, 0.f};

    for (int k0 = 0; k0 < DM; k0 += 64) {
        __syncthreads();
#pragma unroll
        for (int rr = 0; rr < 4; rr++) {
            int idx = rr * 2048 + t * 8;
            int row = idx >> 6, col = idx & 63;
            *(uint4*)&Xs[row][col] = cvt8(X + (size_t)(m0 + row) * DM + k0 + col);
            *(uint4*)&Ws[row][col] = *(const uint4*)(W + (size_t)(n0 + row) * DM + k0 + col);
        }
        __syncthreads();

        bf16x8 af[4][2], bfr[4][2];
#pragma unroll
        for (int mt = 0; mt < 4; mt++) {
            af[mt][0] = *(const bf16x8*)&Xs[mo + mt * 16 + l15][lg * 8];
            af[mt][1] = *(const bf16x8*)&Xs[mo + mt * 16 + l15][32 + lg * 8];
        }
#pragma unroll
        for (int nt = 0; nt < 4; nt++) {
            bfr[nt][0] = *(const bf16x8*)&Ws[no + nt * 16 + l15][lg * 8];
            bfr[nt][1] = *(const bf16x8*)&Ws[no + nt * 16 + l15][32 + lg * 8];
        }
#pragma unroll
        for (int mt = 0; mt < 4; mt++)
#pragma unroll
            for (int nt = 0; nt < 4; nt++) {
                acc[mt][nt] = MFMA16(af[mt][0], bfr[nt][0], acc[mt][nt]);
                acc[mt][nt] = MFMA16(af[mt][1], bfr[nt][1], acc[mt][nt]);
            }
    }

    float bv4[4];
#pragma unroll
    for (int nt = 0; nt < 4; nt++) bv4[nt] = bias[n0 + no + nt * 16 + l15];

    const int h = (n0 + no) >> 6;
    if (z == 2) {
        // transposed V epilogue: vt[bh][d][s]
#pragma unroll
        for (int mt = 0; mt < 4; mt++) {
            int m = m0 + mo + mt * 16 + lg * 4;       // 4-aligned, never crosses b
            int bb = m >> 11, s = m & (SS - 1);
#pragma unroll
            for (int nt = 0; nt < 4; nt++) {
                int d = nt * 16 + l15;
                bf16x4 pk;
#pragma unroll
                for (int r = 0; r < 4; r++) pk[r] = (short)f2bf(acc[mt][nt][r] + bv4[nt]);
                *(bf16x4*)(out + (((size_t)bb * HH + h) * DKK + d) * SS + s) = pk;
            }
        }
    } else {
#pragma unroll
        for (int mt = 0; mt < 4; mt++)
#pragma unroll
            for (int nt = 0; nt < 4; nt++)
#pragma unroll
                for (int r = 0; r < 4; r++) {
                    int m = m0 + mo + mt * 16 + lg * 4 + r;
                    int d = nt * 16 + l15;
                    float v = (acc[mt][nt][r] + bv4[nt]) * scale;
                    int bb = m >> 11, s = m & (SS - 1);
                    out[(((size_t)bb * HH + h) * SS + s) * 64 + d] = f2bf(v);
                }
    }
}

// ---------------------------------------------------------------------------
// Output projection: out[m][n] = sum_k A[m][k]*Wo[n][k] + bo[n]
// A bf16 [16384,512] (ws), Wo fp32 [512,512], out fp32 row-major (d_out).
// ---------------------------------------------------------------------------
__global__ __launch_bounds__(256, 2) void proj_out_mfma(
    const unsigned short* __restrict__ Xb,
    const float* __restrict__ W,
    const float* __restrict__ bias,
    float* __restrict__ out)
{
    __shared__ __align__(16) unsigned short Xs[128][72];
    __shared__ __align__(16) unsigned short Ws[128][72];
    const int t = threadIdx.x;
    const int w = t >> 6, l = t & 63;
    const int l15 = l & 15, lg = l >> 4;
    const int n0 = blockIdx.x * 128, m0 = blockIdx.y * 128;
    const int mo = (w & 1) * 64, no = (w >> 1) * 64;

    f32x4 acc[4][4];
#pragma unroll
    for (int i = 0; i < 4; i++)
#pragma unroll
        for (int j = 0; j < 4; j++) acc[i][j] = (f32x4){0.f, 0.f, 0.f, 0.f};

    for (int k0 = 0; k0 < DM; k0 += 64) {
        __syncthreads();
#pragma unroll
        for (int rr = 0; rr < 4; rr++) {
            int idx = rr * 2048 + t * 8;
            int row = idx >> 6, col = idx & 63;
            *(uint4*)&Xs[row][col] = *(const uint4*)(Xb + (size_t)(m0 + row) * DM + k0 + col);
            *(uint4*)&Ws[row][col] = cvt8(W + (size_t)(n0 + row) * DM + k0 + col);
        }
        __syncthreads();

        bf16x8 af[4][2], bfr[4][2];
#pragma unroll
        for (int mt = 0; mt < 4; mt++) {
            af[mt][0] = *(const bf16x8*)&Xs[mo + mt * 16 + l15][lg * 8];
            af[mt][1] = *(const bf16x8*)&Xs[mo + mt * 16 + l15][32 + lg * 8];
        }
#pragma unroll
        for (int nt = 0; nt < 4; nt++) {
            bfr[nt][0] = *(const bf16x8*)&Ws[no + nt * 16 + l15][lg * 8];
            bfr[nt][1] = *(const bf16x8*)&Ws[no + nt * 16 + l15][32 + lg * 8];
        }
#pragma unroll
        for (int mt = 0; mt < 4; mt++)
#pragma unroll
            for (int nt = 0; nt < 4; nt++) {
                acc[mt][nt] = MFMA16(af[mt][0], bfr[nt][0], acc[mt][nt]);
                acc[mt][nt] = MFMA16(af[mt][1], bfr[nt][1], acc[mt][nt]);
            }
    }

    float bv4[4];
#pragma unroll
    for (int nt = 0; nt < 4; nt++) bv4[nt] = bias[n0 + no + nt * 16 + l15];

#pragma unroll
    for (int mt = 0; mt < 4; mt++)
#pragma unroll
        for (int nt = 0; nt < 4; nt++)
#pragma unroll
            for (int r = 0; r < 4; r++) {
                int m = m0 + mo + mt * 16 + lg * 4 + r;
                int n = n0 + no + nt * 16 + l15;
                out[(size_t)m * DM + n] = acc[mt][nt][r] + bv4[nt];
            }
}

// ---------------------------------------------------------------------------
// Flash attention, bf16 MFMA. Block = (qblock of 128 rows) x (b,h).
// 4 waves; wave w owns q rows [w*32, w*32+32) (NQT=2). kv tiles of 64.
// Grid 1024 blocks -> 4 blocks/CU (round 4 was grid-limited at 2/CU, 20%
// occupancy, VALU-bound at 51% busy). LDS 34.8 KB fits 4 blocks.
// S^T = K·Q^T; softmax exp2-domain; bit-packed mask; defer-max (THR=0).
// l computed by ONES-COLUMN MFMA in PV (Osum = P·1): deletes ls adds,
// 8 shfl/tile and epilogue broadcast shfls; alpha rescale of Osum shares
// O's rescale loop (exact online-softmax semantics).
// __launch_bounds__(256,2): (256,3) caused spills in round 3; live state
// here is ~110 VGPR so the allocator lands ~120 (4 blocks/CU capable).
// ---------------------------------------------------------------------------
__global__ __launch_bounds__(256, 2) void attn_kernel(
    const unsigned short* __restrict__ qw, const unsigned short* __restrict__ kw,
    const unsigned short* __restrict__ vtw,
    const unsigned long long* __restrict__ mb,
    unsigned short* __restrict__ ao)   // [B,S,512] bf16
{
    __shared__ __align__(16) unsigned short Ks[64][72];   // [kv][d]
    __shared__ __align__(16) unsigned short Vt[64][72];   // [d][kv]
    __shared__ __align__(16) unsigned short Pw[4 * 32 * 64]; // per-wave [q][kv] swizzled
    const int t = threadIdx.x;
    const int w = t >> 6, l = t & 63;
    const int l15 = l & 15, lg = l >> 4;
    const int q0 = blockIdx.x * 128;
    const int bh = blockIdx.y;
    const int b = bh >> 3, h = bh & 7;
    const int q0w = q0 + w * 32;
    const unsigned short* qb = qw + (size_t)bh * SS * DKK;
    const unsigned short* kb = kw + (size_t)bh * SS * DKK;
    const unsigned short* vtb = vtw + (size_t)bh * DKK * SS;

    // Per-qt bit-mask row base (row = q0w + qt*16 + l15; 32 words per row)
    const unsigned long long* mbq[2];
#pragma unroll
    for (int qt = 0; qt < 2; qt++)
        mbq[qt] = mb + ((size_t)(q0w + qt * 16 + l15) << 5);

    // Q fragments (B-operand): Qf[qt][dh] = Q[q0w+qt*16+l15][dh*32+lg*8 ..+8]
    bf16x8 Qf[2][2];
#pragma unroll
    for (int qt = 0; qt < 2; qt++)
#pragma unroll
        for (int dh = 0; dh < 2; dh++)
            Qf[qt][dh] = *(const bf16x8*)(qb + (size_t)(q0w + qt * 16 + l15) * DKK + dh * 32 + lg * 8);

    f32x4 O[2][4];    // [qt][dt]: row q = qt*16+lg*4+r, col d = dt*16+l15
    f32x4 Osum[2];    // ones-column accumulator: row sums of P (l denominator)
#pragma unroll
    for (int i = 0; i < 2; i++) {
#pragma unroll
        for (int j = 0; j < 4; j++) O[i][j] = (f32x4){0.f, 0.f, 0.f, 0.f};
        Osum[i] = (f32x4){0.f, 0.f, 0.f, 0.f};
    }
    float m_i[2];
#pragma unroll
    for (int i = 0; i < 2; i++) m_i[i] = -INFINITY;

    const bf16x8 vone = {16256, 16256, 16256, 16256, 16256, 16256, 16256, 16256}; // bf16 1.0 x8
    const int pbase = w * 2048;

    for (int kv0 = 0; kv0 < SS; kv0 += 64) {
        __syncthreads();   // all waves done with Ks/Vt of previous tile
        // ---- stage K tile + (pre-transposed) V tile, clean uint4 copies ----
#pragma unroll
        for (int r = 0; r < 2; r++) {
            int idx = r * 2048 + t * 8;
            int row = idx >> 6, col = idx & 63;
            *(uint4*)&Ks[row][col] = *(const uint4*)(kb + (size_t)(kv0 + row) * DKK + col);
            *(uint4*)&Vt[row][col] = *(const uint4*)(vtb + (size_t)row * SS + kv0 + col);
        }
        __syncthreads();

        // ---- S^T = K·Q^T : S[kvt][qt], row kv = kvt*16+lg*4+r, col q = qt*16+l15
        f32x4 S[4][2];
#pragma unroll
        for (int kvt = 0; kvt < 4; kvt++) {
            bf16x8 ak0 = *(const bf16x8*)&Ks[kvt * 16 + l15][lg * 8];
            bf16x8 ak1 = *(const bf16x8*)&Ks[kvt * 16 + l15][32 + lg * 8];
#pragma unroll
            for (int qt = 0; qt < 2; qt++) {
                f32x4 z = (f32x4){0.f, 0.f, 0.f, 0.f};
                z = MFMA16(ak0, Qf[qt][0], z);
                z = MFMA16(ak1, Qf[qt][1], z);
                S[kvt][qt] = z;
            }
        }

        // ---- mask via packed bits: bit kv_local = kvt*16 + lg*4 + r ----
#pragma unroll
        for (int qt = 0; qt < 2; qt++) {
            unsigned long long mm = mbq[qt][kv0 >> 6];
            unsigned int wlo = (unsigned int)mm;
            unsigned int whi = (unsigned int)(mm >> 32);
            unsigned int u[4];
            u[0] = wlo >> (lg * 4);
            u[1] = wlo >> (16 + lg * 4);
            u[2] = whi >> (lg * 4);
            u[3] = whi >> (16 + lg * 4);
#pragma unroll
            for (int kvt = 0; kvt < 4; kvt++) {
                if (!(u[kvt] & 1u)) S[kvt][qt][0] = -1e38f;
                if (!(u[kvt] & 2u)) S[kvt][qt][1] = -1e38f;
                if (!(u[kvt] & 4u)) S[kvt][qt][2] = -1e38f;
                if (!(u[kvt] & 8u)) S[kvt][qt][3] = -1e38f;
            }
        }

        // ---- online softmax (exp2 domain) with defer-max (THR=0) ----
        float mtl[2];
#pragma unroll
        for (int qt = 0; qt < 2; qt++) {
            // balanced max3 tree over the 16 values (v_max3_f32 fusion)
            float mt = fmaxf(
                max3f(max3f(S[0][qt][0], S[0][qt][1], S[0][qt][2]),
                      max3f(S[0][qt][3], S[1][qt][0], S[1][qt][1]),
                      max3f(S[1][qt][2], S[1][qt][3], S[2][qt][0])),
                fmaxf(max3f(S[2][qt][1], S[2][qt][2], S[2][qt][3]),
                      max3f(S[3][qt][0], S[3][qt][1], fmaxf(S[3][qt][2], S[3][qt][3]))));
            mt = fmaxf(mt, __shfl_xor(mt, 16));
            mt = fmaxf(mt, __shfl_xor(mt, 32));
            mtl[qt] = mt;
        }
        int grow = (mtl[0] > m_i[0]) | (mtl[1] > m_i[1]);
        if (__any(grow)) {
            float alpha[2];
#pragma unroll
            for (int qt = 0; qt < 2; qt++) {
                float mn = fmaxf(m_i[qt], mtl[qt]);
                alpha[qt] = EXP2(m_i[qt] - mn);
                m_i[qt] = mn;
            }
            // rescale O and Osum by alpha (broadcast from q-col lanes to q-row regs)
#pragma unroll
            for (int qt = 0; qt < 2; qt++)
#pragma unroll
                for (int r = 0; r < 4; r++) {
                    float a = __shfl(alpha[qt], lg * 4 + r);
#pragma unroll
                    for (int dt = 0; dt < 4; dt++) O[qt][dt][r] *= a;
                    Osum[qt][r] *= a;
                }
        }

#pragma unroll
        for (int qt = 0; qt < 2; qt++) {
            const int prow = qt * 16 + l15;
            const int swz = (prow & 7) << 3;
#pragma unroll
            for (int kvt = 0; kvt < 4; kvt++) {
                float p0 = EXP2(S[kvt][qt][0] - m_i[qt]);
                float p1 = EXP2(S[kvt][qt][1] - m_i[qt]);
                float p2 = EXP2(S[kvt][qt][2] - m_i[qt]);
                float p3 = EXP2(S[kvt][qt][3] - m_i[qt]);
                bf16x4 pk;
                pk[0] = (short)f2bf(p0); pk[1] = (short)f2bf(p1);
                pk[2] = (short)f2bf(p2); pk[3] = (short)f2bf(p3);
                *(bf16x4*)&Pw[pbase + prow * 64 + ((kvt * 16 + lg * 4) ^ swz)] = pk;
            }
        }

        // Pw is wave-private: per-wave DS ops complete in order, so a block
        // barrier is unnecessary. The fence stops the compiler from hoisting
        // the ap reads above the pk stores.
        asm volatile("s_waitcnt lgkmcnt(0)" ::: "memory");

        // ---- O += P·V ; Osum += P·1 (row sums == softmax denominator) ----
        bf16x8 bv2[4][2];
#pragma unroll
        for (int dt = 0; dt < 4; dt++) {
            bv2[dt][0] = *(const bf16x8*)&Vt[dt * 16 + l15][lg * 8];
            bv2[dt][1] = *(const bf16x8*)&Vt[dt * 16 + l15][32 + lg * 8];
        }
#pragma unroll
        for (int qt = 0; qt < 2; qt++) {
            const int prow = qt * 16 + l15;
            const int swz = (prow & 7) << 3;
            bf16x8 ap0 = *(const bf16x8*)&Pw[pbase + prow * 64 + ((lg * 8) ^ swz)];
            bf16x8 ap1 = *(const bf16x8*)&Pw[pbase + prow * 64 + ((32 + lg * 8) ^ swz)];
#pragma unroll
            for (int dt = 0; dt < 4; dt++) {
                O[qt][dt] = MFMA16(ap0, bv2[dt][0], O[qt][dt]);
                O[qt][dt] = MFMA16(ap1, bv2[dt][1], O[qt][dt]);
            }
            Osum[qt] = MFMA16(ap0, vone, Osum[qt]);
            Osum[qt] = MFMA16(ap1, vone, Osum[qt]);
        }
    }

    // ---- epilogue: normalize by Osum (per-lane, no shfl), store bf16 ----
#pragma unroll
    for (int qt = 0; qt < 2; qt++) {
#pragma unroll
        for (int r = 0; r < 4; r++) {
            float lv = 1.f / Osum[qt][r];
            int q = q0w + qt * 16 + lg * 4 + r;
            size_t base = ((size_t)b * SS + q) * DM + h * 64;
#pragma unroll
            for (int dt = 0; dt < 4; dt++)
                ao[base + dt * 16 + l15] = f2bf(O[qt][dt][r] * lv);
        }
    }
}

extern "C" void kernel_launch(void* const* d_in, const int* in_sizes, int n_in,
                              void* d_out, int out_size, void* d_ws, size_t ws_size,
                              hipStream_t stream) {
    // All float tensors are fp32 (proven). mask is int32.
    const float* Q    = (const float*)d_in[0];
    const float* K    = (const float*)d_in[1];
    const float* V    = (const float*)d_in[2];
    const int*   mask = (const int*)d_in[3];
    const float* Wq   = (const float*)d_in[4];
    const float* bq   = (const float*)d_in[5];
    const float* Wk   = (const float*)d_in[6];
    const float* bk   = (const float*)d_in[7];
    const float* Wv   = (const float*)d_in[8];
    const float* bv   = (const float*)d_in[9];
    const float* Wo   = (const float*)d_in[10];
    const float* bo   = (const float*)d_in[11];

    // ws: [qb 16 MB][kb 16 MB][vtb 16 MB][ab 16 MB] = 64 MB (proven-safe).
    // vtb holds V ALREADY TRANSPOSED ([bh][64][S]). ab head doubles as the
    // bf16-W scratch (1.5 MB): written by w_cvt, read by proj_qkv_fused,
    // then fully overwritten by attn's output (stream-ordered, safe).
    const size_t SEG = (size_t)BB * HH * SS * DKK;  // 8,388,608 bf16 elems
    unsigned short* qb  = (unsigned short*)d_ws;
    unsigned short* kb  = qb + SEG;
    unsigned short* vtb = kb + SEG;
    unsigned short* ab  = vtb + SEG;
    unsigned short* wb  = ab;   // 3 x 262144 bf16 = 1.5 MB, dead before attn

    const size_t MB_BYTES = (size_t)SS * (SS / 64) * sizeof(unsigned long long); // 524288
    unsigned long long* mbits =
        (unsigned long long*)((char*)d_out + (size_t)out_size - MB_BYTES);

    const float qscale = 0.125f * 1.44269504088896340736f;  // 1/sqrt(dk) * log2(e)

    mask_pack<<<dim3((SS * (SS / 64)) / 4), 256, 0, stream>>>(mask, mbits);
    w_cvt<<<dim3(384), 256, 0, stream>>>(Wq, Wk, Wv, wb);

    dim3 gp(DM / 128, (BB * SS) / 128, 3);  // (4, 128, 3)
    proj_qkv_fused<<<gp, 256, 0, stream>>>(Q, K, V, wb, bq, bk, bv, qb, qscale);

    attn_kernel<<<dim3(SS / 128, BB * HH), 256, 0, stream>>>(qb, kb, vtb, mbits, ab);

    proj_out_mfma<<<dim3(DM / 128, (BB * SS) / 128), 256, 0, stream>>>(ab, Wo, bo, (float*)d_out);
}

// Round 7
// 375.510 us; speedup vs baseline: 1.9172x; 1.0456x over previous
//
#include <hip/hip_runtime.h>
#include <hip/hip_bf16.h>
#include <math.h>

#define BB 8
#define SS 2048
#define HH 8
#define DKK 64
#define DM 512

typedef short bf16x8 __attribute__((ext_vector_type(8)));
typedef short bf16x4 __attribute__((ext_vector_type(4)));
typedef float f32x4 __attribute__((ext_vector_type(4)));
#define MFMA16(a, b, c) __builtin_amdgcn_mfma_f32_16x16x32_bf16(a, b, c, 0, 0, 0)

#if __has_builtin(__builtin_amdgcn_exp2f)
#define EXP2(x) __builtin_amdgcn_exp2f(x)
#else
#define EXP2(x) exp2f(x)
#endif

__device__ __forceinline__ unsigned short f2bf(float f) {
    __hip_bfloat16 h = __float2bfloat16(f);
    return *reinterpret_cast<unsigned short*>(&h);
}

__device__ __forceinline__ float max3f(float a, float b, float c) {
    return fmaxf(fmaxf(a, b), c);   // clang fuses to v_max3_f32
}

// Convert 8 consecutive fp32 -> 8 bf16, return as uint4 for a 16B LDS store.
__device__ __forceinline__ uint4 cvt8(const float* __restrict__ src) {
    float4 a = *(const float4*)src;
    float4 b = *(const float4*)(src + 4);
    unsigned short tmp[8];
    tmp[0] = f2bf(a.x); tmp[1] = f2bf(a.y); tmp[2] = f2bf(a.z); tmp[3] = f2bf(a.w);
    tmp[4] = f2bf(b.x); tmp[5] = f2bf(b.y); tmp[6] = f2bf(b.z); tmp[7] = f2bf(b.w);
    return *(uint4*)tmp;
}

// ---------------------------------------------------------------------------
// Mask bit-pack: mask int32 [S][S] -> mb uint64 [S][S/64], bit i of word
// (q, c) = (mask[q][c*64+i] != 0). One wave per output word via __ballot.
// ---------------------------------------------------------------------------
__global__ __launch_bounds__(256) void mask_pack(
    const int* __restrict__ mask, unsigned long long* __restrict__ mb)
{
    const int t = threadIdx.x;
    const int wid = (blockIdx.x << 2) | (t >> 6);   // global wave id == word idx
    const int lane = t & 63;
    const int q = wid >> 5;          // / (SS/64)
    const int c = wid & 31;
    int e = mask[(size_t)q * SS + (c << 6) + lane];
    unsigned long long bal = __ballot(e != 0);
    if (lane == 0) mb[wid] = bal;
}

// ---------------------------------------------------------------------------
// W pre-convert: Wq/Wk/Wv fp32 [512][512] -> bf16, same layout, packed into
// dst (3 x 262144 elems = 1.5 MB).
// ---------------------------------------------------------------------------
__global__ __launch_bounds__(256) void w_cvt(
    const float* __restrict__ Wq, const float* __restrict__ Wk,
    const float* __restrict__ Wv, unsigned short* __restrict__ dst)
{
    const int idx = blockIdx.x * 256 + threadIdx.x;   // 0..98303
    const int which = idx >> 15;                       // / 32768
    const int off = (idx & 32767) * 8;
    const float* src = (which == 0) ? Wq : (which == 1) ? Wk : Wv;
    *(uint4*)(dst + (size_t)which * 262144 + off) = cvt8(src + off);
}

// ---------------------------------------------------------------------------
// Fused QKV projection (gridDim.z selects Q/K/V): out[m][n] =
// (sum_k X[m][k]*W[n][k] + bias[n]) * scale. W comes PRE-CONVERTED bf16
// (uint4-copy staging); X is fp32 (cvt8 staging).
// z=0 (Q), z=1 (K): out bf16 scattered to [B*H][S][64] (n = h*64+d).
// z=2 (V): out written TRANSPOSED to [B*H][64][S].
// ---------------------------------------------------------------------------
__global__ __launch_bounds__(256, 2) void proj_qkv_fused(
    const float* __restrict__ Xq, const float* __restrict__ Xk, const float* __restrict__ Xv,
    const unsigned short* __restrict__ Wb,
    const float* __restrict__ bq, const float* __restrict__ bk, const float* __restrict__ bv,
    unsigned short* __restrict__ outbase, float qscale)
{
    const int z = blockIdx.z;
    const float* X = (z == 0) ? Xq : (z == 1) ? Xk : Xv;
    const unsigned short* W = Wb + (size_t)z * 262144;
    const float* bias = (z == 0) ? bq : (z == 1) ? bk : bv;
    unsigned short* out = outbase + (size_t)z * ((size_t)BB * HH * SS * DKK);
    const float scale = (z == 0) ? qscale : 1.0f;

    __shared__ __align__(16) unsigned short Xs[128][72];
    __shared__ __align__(16) unsigned short Ws[128][72];
    const int t = threadIdx.x;
    const int w = t >> 6, l = t & 63;
    const int l15 = l & 15, lg = l >> 4;
    const int n0 = blockIdx.x * 128, m0 = blockIdx.y * 128;
    const int mo = (w & 1) * 64, no = (w >> 1) * 64;

    f32x4 acc[4][4];
#pragma unroll
    for (int i = 0; i < 4; i++)
#pragma unroll
        for (int j = 0; j < 4; j++) acc[i][j] = (f32x4){0.f, 0.f, 0.f, 0.f};

    for (int k0 = 0; k0 < DM; k0 += 64) {
        __syncthreads();
#pragma unroll
        for (int rr = 0; rr < 4; rr++) {
            int idx = rr * 2048 + t * 8;
            int row = idx >> 6, col = idx & 63;
            *(uint4*)&Xs[row][col] = cvt8(X + (size_t)(m0 + row) * DM + k0 + col);
            *(uint4*)&Ws[row][col] = *(const uint4*)(W + (size_t)(n0 + row) * DM + k0 + col);
        }
        __syncthreads();

        bf16x8 af[4][2], bfr[4][2];
#pragma unroll
        for (int mt = 0; mt < 4; mt++) {
            af[mt][0] = *(const bf16x8*)&Xs[mo + mt * 16 + l15][lg * 8];
            af[mt][1] = *(const bf16x8*)&Xs[mo + mt * 16 + l15][32 + lg * 8];
        }
#pragma unroll
        for (int nt = 0; nt < 4; nt++) {
            bfr[nt][0] = *(const bf16x8*)&Ws[no + nt * 16 + l15][lg * 8];
            bfr[nt][1] = *(const bf16x8*)&Ws[no + nt * 16 + l15][32 + lg * 8];
        }
#pragma unroll
        for (int mt = 0; mt < 4; mt++)
#pragma unroll
            for (int nt = 0; nt < 4; nt++) {
                acc[mt][nt] = MFMA16(af[mt][0], bfr[nt][0], acc[mt][nt]);
                acc[mt][nt] = MFMA16(af[mt][1], bfr[nt][1], acc[mt][nt]);
            }
    }

    float bv4[4];
#pragma unroll
    for (int nt = 0; nt < 4; nt++) bv4[nt] = bias[n0 + no + nt * 16 + l15];

    const int h = (n0 + no) >> 6;
    if (z == 2) {
        // transposed V epilogue: vt[bh][d][s]
#pragma unroll
        for (int mt = 0; mt < 4; mt++) {
            int m = m0 + mo + mt * 16 + lg * 4;       // 4-aligned, never crosses b
            int bb = m >> 11, s = m & (SS - 1);
#pragma unroll
            for (int nt = 0; nt < 4; nt++) {
                int d = nt * 16 + l15;
                bf16x4 pk;
#pragma unroll
                for (int r = 0; r < 4; r++) pk[r] = (short)f2bf(acc[mt][nt][r] + bv4[nt]);
                *(bf16x4*)(out + (((size_t)bb * HH + h) * DKK + d) * SS + s) = pk;
            }
        }
    } else {
#pragma unroll
        for (int mt = 0; mt < 4; mt++)
#pragma unroll
            for (int nt = 0; nt < 4; nt++)
#pragma unroll
                for (int r = 0; r < 4; r++) {
                    int m = m0 + mo + mt * 16 + lg * 4 + r;
                    int d = nt * 16 + l15;
                    float v = (acc[mt][nt][r] + bv4[nt]) * scale;
                    int bb = m >> 11, s = m & (SS - 1);
                    out[(((size_t)bb * HH + h) * SS + s) * 64 + d] = f2bf(v);
                }
    }
}

// ---------------------------------------------------------------------------
// Output projection: out[m][n] = sum_k A[m][k]*Wo[n][k] + bo[n]
// A bf16 [16384,512] (ws), Wo fp32 [512,512], out fp32 row-major (d_out).
// ---------------------------------------------------------------------------
__global__ __launch_bounds__(256, 2) void proj_out_mfma(
    const unsigned short* __restrict__ Xb,
    const float* __restrict__ W,
    const float* __restrict__ bias,
    float* __restrict__ out)
{
    __shared__ __align__(16) unsigned short Xs[128][72];
    __shared__ __align__(16) unsigned short Ws[128][72];
    const int t = threadIdx.x;
    const int w = t >> 6, l = t & 63;
    const int l15 = l & 15, lg = l >> 4;
    const int n0 = blockIdx.x * 128, m0 = blockIdx.y * 128;
    const int mo = (w & 1) * 64, no = (w >> 1) * 64;

    f32x4 acc[4][4];
#pragma unroll
    for (int i = 0; i < 4; i++)
#pragma unroll
        for (int j = 0; j < 4; j++) acc[i][j] = (f32x4){0.f, 0.f, 0.f, 0.f};

    for (int k0 = 0; k0 < DM; k0 += 64) {
        __syncthreads();
#pragma unroll
        for (int rr = 0; rr < 4; rr++) {
            int idx = rr * 2048 + t * 8;
            int row = idx >> 6, col = idx & 63;
            *(uint4*)&Xs[row][col] = *(const uint4*)(Xb + (size_t)(m0 + row) * DM + k0 + col);
            *(uint4*)&Ws[row][col] = cvt8(W + (size_t)(n0 + row) * DM + k0 + col);
        }
        __syncthreads();

        bf16x8 af[4][2], bfr[4][2];
#pragma unroll
        for (int mt = 0; mt < 4; mt++) {
            af[mt][0] = *(const bf16x8*)&Xs[mo + mt * 16 + l15][lg * 8];
            af[mt][1] = *(const bf16x8*)&Xs[mo + mt * 16 + l15][32 + lg * 8];
        }
#pragma unroll
        for (int nt = 0; nt < 4; nt++) {
            bfr[nt][0] = *(const bf16x8*)&Ws[no + nt * 16 + l15][lg * 8];
            bfr[nt][1] = *(const bf16x8*)&Ws[no + nt * 16 + l15][32 + lg * 8];
        }
#pragma unroll
        for (int mt = 0; mt < 4; mt++)
#pragma unroll
            for (int nt = 0; nt < 4; nt++) {
                acc[mt][nt] = MFMA16(af[mt][0], bfr[nt][0], acc[mt][nt]);
                acc[mt][nt] = MFMA16(af[mt][1], bfr[nt][1], acc[mt][nt]);
            }
    }

    float bv4[4];
#pragma unroll
    for (int nt = 0; nt < 4; nt++) bv4[nt] = bias[n0 + no + nt * 16 + l15];

#pragma unroll
    for (int mt = 0; mt < 4; mt++)
#pragma unroll
        for (int nt = 0; nt < 4; nt++)
#pragma unroll
            for (int r = 0; r < 4; r++) {
                int m = m0 + mo + mt * 16 + lg * 4 + r;
                int n = n0 + no + nt * 16 + l15;
                out[(size_t)m * DM + n] = acc[mt][nt][r] + bv4[nt];
            }
}

// ---------------------------------------------------------------------------
// Flash attention, bf16 MFMA. Block = (qblock of 256 rows) x (b,h), 512 thr.
// 8 waves; wave w owns q rows [w*32, w*32+32) (NQT=2). kv tiles of 64.
// Rationale (round-5 post-mortem): per-tile cost = fixed (K/V staging, Vt
// fragment loads, loop) + variable (proportional to qt). Round 5 halved
// blocks' qt but doubled block count -> fixed part doubled. 512-thread
// blocks keep qt=2 waves AND round-4 staging totals: staging per thread
// halves (1 uint4/buffer), 16 waves/CU at 2 blocks/CU.
// S^T = K·Q^T; softmax exp2-domain; bit-packed mask; defer-max (THR=0).
// l via ones-column MFMA (Osum = P·1). Pw swizzled, wave-private.
// __launch_bounds__(512,4) caps VGPR at 128 (live state ~84, no spill).
// ---------------------------------------------------------------------------
__global__ __launch_bounds__(512, 4) void attn_kernel(
    const unsigned short* __restrict__ qw, const unsigned short* __restrict__ kw,
    const unsigned short* __restrict__ vtw,
    const unsigned long long* __restrict__ mb,
    unsigned short* __restrict__ ao)   // [B,S,512] bf16
{
    __shared__ __align__(16) unsigned short Ks[64][72];   // [kv][d]
    __shared__ __align__(16) unsigned short Vt[64][72];   // [d][kv]
    __shared__ __align__(16) unsigned short Pw[8 * 32 * 64]; // per-wave [q][kv] swizzled
    const int t = threadIdx.x;
    const int w = t >> 6, l = t & 63;
    const int l15 = l & 15, lg = l >> 4;
    const int q0 = blockIdx.x * 256;
    const int bh = blockIdx.y;
    const int b = bh >> 3, h = bh & 7;
    const int q0w = q0 + w * 32;
    const unsigned short* qb = qw + (size_t)bh * SS * DKK;
    const unsigned short* kb = kw + (size_t)bh * SS * DKK;
    const unsigned short* vtb = vtw + (size_t)bh * DKK * SS;

    // Per-qt bit-mask row base (row = q0w + qt*16 + l15; 32 words per row)
    const unsigned long long* mbq[2];
#pragma unroll
    for (int qt = 0; qt < 2; qt++)
        mbq[qt] = mb + ((size_t)(q0w + qt * 16 + l15) << 5);

    // Q fragments (B-operand): Qf[qt][dh] = Q[q0w+qt*16+l15][dh*32+lg*8 ..+8]
    bf16x8 Qf[2][2];
#pragma unroll
    for (int qt = 0; qt < 2; qt++)
#pragma unroll
        for (int dh = 0; dh < 2; dh++)
            Qf[qt][dh] = *(const bf16x8*)(qb + (size_t)(q0w + qt * 16 + l15) * DKK + dh * 32 + lg * 8);

    f32x4 O[2][4];    // [qt][dt]: row q = qt*16+lg*4+r, col d = dt*16+l15
    f32x4 Osum[2];    // ones-column accumulator: row sums of P (l denominator)
#pragma unroll
    for (int i = 0; i < 2; i++) {
#pragma unroll
        for (int j = 0; j < 4; j++) O[i][j] = (f32x4){0.f, 0.f, 0.f, 0.f};
        Osum[i] = (f32x4){0.f, 0.f, 0.f, 0.f};
    }
    float m_i[2];
#pragma unroll
    for (int i = 0; i < 2; i++) m_i[i] = -INFINITY;

    const bf16x8 vone = {16256, 16256, 16256, 16256, 16256, 16256, 16256, 16256}; // bf16 1.0 x8
    const int pbase = w * 2048;

    for (int kv0 = 0; kv0 < SS; kv0 += 64) {
        __syncthreads();   // all waves done with Ks/Vt of previous tile
        // ---- stage K tile + (pre-transposed) V tile: 1 uint4/thread each ----
        {
            int idx = t * 8;                 // 512 threads x 8 shorts = 64x64
            int row = idx >> 6, col = idx & 63;
            *(uint4*)&Ks[row][col] = *(const uint4*)(kb + (size_t)(kv0 + row) * DKK + col);
            *(uint4*)&Vt[row][col] = *(const uint4*)(vtb + (size_t)row * SS + kv0 + col);
        }
        __syncthreads();

        // ---- S^T = K·Q^T : S[kvt][qt], row kv = kvt*16+lg*4+r, col q = qt*16+l15
        f32x4 S[4][2];
#pragma unroll
        for (int kvt = 0; kvt < 4; kvt++) {
            bf16x8 ak0 = *(const bf16x8*)&Ks[kvt * 16 + l15][lg * 8];
            bf16x8 ak1 = *(const bf16x8*)&Ks[kvt * 16 + l15][32 + lg * 8];
#pragma unroll
            for (int qt = 0; qt < 2; qt++) {
                f32x4 z = (f32x4){0.f, 0.f, 0.f, 0.f};
                z = MFMA16(ak0, Qf[qt][0], z);
                z = MFMA16(ak1, Qf[qt][1], z);
                S[kvt][qt] = z;
            }
        }

        // ---- mask via packed bits: bit kv_local = kvt*16 + lg*4 + r ----
#pragma unroll
        for (int qt = 0; qt < 2; qt++) {
            unsigned long long mm = mbq[qt][kv0 >> 6];
            unsigned int wlo = (unsigned int)mm;
            unsigned int whi = (unsigned int)(mm >> 32);
            unsigned int u[4];
            u[0] = wlo >> (lg * 4);
            u[1] = wlo >> (16 + lg * 4);
            u[2] = whi >> (lg * 4);
            u[3] = whi >> (16 + lg * 4);
#pragma unroll
            for (int kvt = 0; kvt < 4; kvt++) {
                if (!(u[kvt] & 1u)) S[kvt][qt][0] = -1e38f;
                if (!(u[kvt] & 2u)) S[kvt][qt][1] = -1e38f;
                if (!(u[kvt] & 4u)) S[kvt][qt][2] = -1e38f;
                if (!(u[kvt] & 8u)) S[kvt][qt][3] = -1e38f;
            }
        }

        // ---- online softmax (exp2 domain) with defer-max (THR=0) ----
        float mtl[2];
#pragma unroll
        for (int qt = 0; qt < 2; qt++) {
            // balanced max3 tree over the 16 values (v_max3_f32 fusion)
            float mt = fmaxf(
                max3f(max3f(S[0][qt][0], S[0][qt][1], S[0][qt][2]),
                      max3f(S[0][qt][3], S[1][qt][0], S[1][qt][1]),
                      max3f(S[1][qt][2], S[1][qt][3], S[2][qt][0])),
                fmaxf(max3f(S[2][qt][1], S[2][qt][2], S[2][qt][3]),
                      max3f(S[3][qt][0], S[3][qt][1], fmaxf(S[3][qt][2], S[3][qt][3]))));
            mt = fmaxf(mt, __shfl_xor(mt, 16));
            mt = fmaxf(mt, __shfl_xor(mt, 32));
            mtl[qt] = mt;
        }
        int grow = (mtl[0] > m_i[0]) | (mtl[1] > m_i[1]);
        if (__any(grow)) {
            float alpha[2];
#pragma unroll
            for (int qt = 0; qt < 2; qt++) {
                float mn = fmaxf(m_i[qt], mtl[qt]);
                alpha[qt] = EXP2(m_i[qt] - mn);
                m_i[qt] = mn;
            }
            // rescale O and Osum by alpha (broadcast from q-col lanes to q-row regs)
#pragma unroll
            for (int qt = 0; qt < 2; qt++)
#pragma unroll
                for (int r = 0; r < 4; r++) {
                    float a = __shfl(alpha[qt], lg * 4 + r);
#pragma unroll
                    for (int dt = 0; dt < 4; dt++) O[qt][dt][r] *= a;
                    Osum[qt][r] *= a;
                }
        }

#pragma unroll
        for (int qt = 0; qt < 2; qt++) {
            const int prow = qt * 16 + l15;
            const int swz = (prow & 7) << 3;
#pragma unroll
            for (int kvt = 0; kvt < 4; kvt++) {
                float p0 = EXP2(S[kvt][qt][0] - m_i[qt]);
                float p1 = EXP2(S[kvt][qt][1] - m_i[qt]);
                float p2 = EXP2(S[kvt][qt][2] - m_i[qt]);
                float p3 = EXP2(S[kvt][qt][3] - m_i[qt]);
                bf16x4 pk;
                pk[0] = (short)f2bf(p0); pk[1] = (short)f2bf(p1);
                pk[2] = (short)f2bf(p2); pk[3] = (short)f2bf(p3);
                *(bf16x4*)&Pw[pbase + prow * 64 + ((kvt * 16 + lg * 4) ^ swz)] = pk;
            }
        }

        // Pw is wave-private: per-wave DS ops complete in order, so a block
        // barrier is unnecessary. The fence stops the compiler from hoisting
        // the ap reads above the pk stores.
        asm volatile("s_waitcnt lgkmcnt(0)" ::: "memory");

        // ---- O += P·V ; Osum += P·1 (row sums == softmax denominator) ----
        bf16x8 bv2[4][2];
#pragma unroll
        for (int dt = 0; dt < 4; dt++) {
            bv2[dt][0] = *(const bf16x8*)&Vt[dt * 16 + l15][lg * 8];
            bv2[dt][1] = *(const bf16x8*)&Vt[dt * 16 + l15][32 + lg * 8];
        }
#pragma unroll
        for (int qt = 0; qt < 2; qt++) {
            const int prow = qt * 16 + l15;
            const int swz = (prow & 7) << 3;
            bf16x8 ap0 = *(const bf16x8*)&Pw[pbase + prow * 64 + ((lg * 8) ^ swz)];
            bf16x8 ap1 = *(const bf16x8*)&Pw[pbase + prow * 64 + ((32 + lg * 8) ^ swz)];
#pragma unroll
            for (int dt = 0; dt < 4; dt++) {
                O[qt][dt] = MFMA16(ap0, bv2[dt][0], O[qt][dt]);
                O[qt][dt] = MFMA16(ap1, bv2[dt][1], O[qt][dt]);
            }
            Osum[qt] = MFMA16(ap0, vone, Osum[qt]);
            Osum[qt] = MFMA16(ap1, vone, Osum[qt]);
        }
    }

    // ---- epilogue: normalize by Osum (per-lane, no shfl), store bf16 ----
#pragma unroll
    for (int qt = 0; qt < 2; qt++) {
#pragma unroll
        for (int r = 0; r < 4; r++) {
            float lv = 1.f / Osum[qt][r];
            int q = q0w + qt * 16 + lg * 4 + r;
            size_t base = ((size_t)b * SS + q) * DM + h * 64;
#pragma unroll
            for (int dt = 0; dt < 4; dt++)
                ao[base + dt * 16 + l15] = f2bf(O[qt][dt][r] * lv);
        }
    }
}

extern "C" void kernel_launch(void* const* d_in, const int* in_sizes, int n_in,
                              void* d_out, int out_size, void* d_ws, size_t ws_size,
                              hipStream_t stream) {
    // All float tensors are fp32 (proven). mask is int32.
    const float* Q    = (const float*)d_in[0];
    const float* K    = (const float*)d_in[1];
    const float* V    = (const float*)d_in[2];
    const int*   mask = (const int*)d_in[3];
    const float* Wq   = (const float*)d_in[4];
    const float* bq   = (const float*)d_in[5];
    const float* Wk   = (const float*)d_in[6];
    const float* bk   = (const float*)d_in[7];
    const float* Wv   = (const float*)d_in[8];
    const float* bv   = (const float*)d_in[9];
    const float* Wo   = (const float*)d_in[10];
    const float* bo   = (const float*)d_in[11];

    // ws: [qb 16 MB][kb 16 MB][vtb 16 MB][ab 16 MB] = 64 MB (proven-safe).
    // vtb holds V ALREADY TRANSPOSED ([bh][64][S]). ab head doubles as the
    // bf16-W scratch (1.5 MB): written by w_cvt, read by proj_qkv_fused,
    // then fully overwritten by attn's output (stream-ordered, safe).
    const size_t SEG = (size_t)BB * HH * SS * DKK;  // 8,388,608 bf16 elems
    unsigned short* qb  = (unsigned short*)d_ws;
    unsigned short* kb  = qb + SEG;
    unsigned short* vtb = kb + SEG;
    unsigned short* ab  = vtb + SEG;
    unsigned short* wb  = ab;   // 3 x 262144 bf16 = 1.5 MB, dead before attn

    const size_t MB_BYTES = (size_t)SS * (SS / 64) * sizeof(unsigned long long); // 524288
    unsigned long long* mbits =
        (unsigned long long*)((char*)d_out + (size_t)out_size - MB_BYTES);

    const float qscale = 0.125f * 1.44269504088896340736f;  // 1/sqrt(dk) * log2(e)

    mask_pack<<<dim3((SS * (SS / 64)) / 4), 256, 0, stream>>>(mask, mbits);
    w_cvt<<<dim3(384), 256, 0, stream>>>(Wq, Wk, Wv, wb);

    dim3 gp(DM / 128, (BB * SS) / 128, 3);  // (4, 128, 3)
    proj_qkv_fused<<<gp, 256, 0, stream>>>(Q, K, V, wb, bq, bk, bv, qb, qscale);

    attn_kernel<<<dim3(SS / 256, BB * HH), 512, 0, stream>>>(qb, kb, vtb, mbits, ab);

    proj_out_mfma<<<dim3(DM / 128, (BB * SS) / 128), 256, 0, stream>>>(ab, Wo, bo, (float*)d_out);
}